// Round 4
// baseline (8768.368 us; speedup 1.0000x reference)
//
#include <hip/hip_runtime.h>
#include <hip/hip_bf16.h>
#include <cstddef>
#include <cstdint>

#define DEVINL __device__ __forceinline__

constexpr int Bn = 128;   // batch
constexpr int Tn = 512;   // time
constexpr int Fn = 512;   // features
constexpr int Un = 256;   // units
constexpr int Gn = 1024;  // 4*U
constexpr int RS = 5;     // ring slots

typedef float vf2 __attribute__((ext_vector_type(2)));
typedef short bf16x8 __attribute__((ext_vector_type(8)));
typedef float f32x4 __attribute__((ext_vector_type(4)));

DEVINL float ftanh(float x) { float e = __expf(2.f * x); return 1.f - 2.f / (e + 1.f); }
DEVINL float hsig(float x)  { return fminf(fmaxf(fmaf(x, 0.2f, 0.5f), 0.f), 1.f); }

DEVINL void softmax4(float* s) {
    float mx = fmaxf(fmaxf(s[0], s[1]), fmaxf(s[2], s[3]));
    float e0 = __expf(s[0] - mx), e1 = __expf(s[1] - mx);
    float e2 = __expf(s[2] - mx), e3 = __expf(s[3] - mx);
    float inv = 1.f / (e0 + e1 + e2 + e3);
    s[0] = e0 * inv; s[1] = e1 * inv; s[2] = e2 * inv; s[3] = e3 * inv;
}

DEVINL vf2 fma2(vf2 a, vf2 b, vf2 c) {
#if __has_builtin(__builtin_elementwise_fma)
    return __builtin_elementwise_fma(a, b, c);
#else
    vf2 r; r.x = fmaf(a.x, b.x, c.x); r.y = fmaf(a.y, b.y, c.y); return r;
#endif
}

// ---------------- fp8 e4m3 encode/decode (HW path on gfx950) ----------------
#if __has_builtin(__builtin_amdgcn_cvt_pk_f32_fp8) && __has_builtin(__builtin_amdgcn_cvt_pk_fp8_f32)
#define HW_FP8 1
#else
#define HW_FP8 0
#endif

#if !HW_FP8
DEVINL float e4m3_dec1(unsigned int b) {
    unsigned int s = b >> 7, E = (b >> 3) & 15, m = b & 7;
    float f = E ? __builtin_ldexpf(1.f + (float)m * 0.125f, (int)E - 7)
                : __builtin_ldexpf((float)m, -9);
    return s ? -f : f;
}
DEVINL unsigned int e4m3_enc1(float f) {
    unsigned int s = (__builtin_bit_cast(unsigned int, f) >> 31) << 7;
    float a = fabsf(f);
    if (!(a > 0.f)) return s;
    if (a >= 448.f) return s | 0x7E;
    int e; float m = frexpf(a, &e);
    int E = e + 6;
    if (E >= 1) {
        int q = (int)rintf((2.f * m - 1.f) * 8.f);
        if (q == 8) { E++; q = 0; if (E > 15) return s | 0x7E; }
        return s | ((unsigned)E << 3) | (unsigned)q;
    }
    int q = (int)rintf(a * 512.f);
    if (q > 7) return s | (1u << 3);
    return s | (unsigned)q;
}
#endif

DEVINL vf2 cvt2lo(unsigned int u) {
#if HW_FP8
    return __builtin_amdgcn_cvt_pk_f32_fp8((int)u, false);
#else
    vf2 r; r.x = e4m3_dec1(u & 255); r.y = e4m3_dec1((u >> 8) & 255); return r;
#endif
}
DEVINL vf2 cvt2hi(unsigned int u) {
#if HW_FP8
    return __builtin_amdgcn_cvt_pk_f32_fp8((int)u, true);
#else
    vf2 r; r.x = e4m3_dec1((u >> 16) & 255); r.y = e4m3_dec1((u >> 24) & 255); return r;
#endif
}
DEVINL unsigned int enc2lo(float a, float b, unsigned int old) {
#if HW_FP8
    return (unsigned int)__builtin_amdgcn_cvt_pk_fp8_f32(a, b, (int)old, false);
#else
    return (old & 0xFFFF0000u) | (e4m3_enc1(a) | (e4m3_enc1(b) << 8));
#endif
}
DEVINL unsigned int enc2hi(float a, float b, unsigned int old) {
#if HW_FP8
    return (unsigned int)__builtin_amdgcn_cvt_pk_fp8_f32(a, b, (int)old, true);
#else
    return (old & 0x0000FFFFu) | ((e4m3_enc1(a) | (e4m3_enc1(b) << 8)) << 16);
#endif
}

DEVINL unsigned short f2bf(float f) {  // round-to-nearest-even bf16
    unsigned int u = __builtin_bit_cast(unsigned int, f);
    u += 0x7fffu + ((u >> 16) & 1u);
    return (unsigned short)(u >> 16);
}

// ---------------------------------------------------------------------------
// pack x (fp32) -> bf16, same layout
// ---------------------------------------------------------------------------
__global__ __launch_bounds__(256)
void pack_x(const float* __restrict__ x, unsigned short* __restrict__ xbf)
{
    size_t i = ((size_t)blockIdx.x * 256 + threadIdx.x) * 4;
    float4 v = *(const float4*)(x + i);
    ushort4 o;
    o.x = f2bf(v.x); o.y = f2bf(v.y); o.z = f2bf(v.z); o.w = f2bf(v.w);
    *(ushort4*)(xbf + i) = o;
}

// ---------------------------------------------------------------------------
// pack W (K=512 rows x N cols, fp32) -> Wt (N rows x 512 cols, bf16)
// ---------------------------------------------------------------------------
__global__ __launch_bounds__(256)
void wt_pack(const float* __restrict__ W, unsigned short* __restrict__ Wt, int N)
{
    int total = N * 512;
    for (int e = blockIdx.x * 256 + threadIdx.x; e < total; e += gridDim.x * 256) {
        int n = e >> 9, k = e & 511;
        Wt[e] = f2bf(W[(size_t)k * N + n]);
    }
}

// ---------------------------------------------------------------------------
// pack recurrence weights -> fp8 e4m3 at x16 scale, k-interleaved (8 k per
// uint2): P[kc*N + n] (uint2) holds W[kc*8+0..7][n] * 16.
// ---------------------------------------------------------------------------
__global__ __launch_bounds__(256)
void pack_w8(const float* __restrict__ rk, const float* __restrict__ ath,
             const float* __restrict__ atc,
             uint2* __restrict__ rk8, uint2* __restrict__ Wh8, uint2* __restrict__ Wc8)
{
    const int idx = blockIdx.x * 256 + threadIdx.x;
    // items: rk 32*1024, Wh 32*256, Wc 32*256
    for (int e = idx; e < 32 * 1024 + 2 * 32 * 256; e += gridDim.x * 256) {
        const float* src; uint2* dst; int kc, n, N;
        if (e < 32 * 1024) { src = rk; dst = rk8; N = 1024; kc = e >> 10; n = e & 1023; }
        else if (e < 32 * 1024 + 32 * 256) { int e2 = e - 32 * 1024; src = ath; dst = Wh8; N = 256; kc = e2 >> 8; n = e2 & 255; }
        else { int e2 = e - 32 * 1024 - 32 * 256; src = atc; dst = Wc8; N = 256; kc = e2 >> 8; n = e2 & 255; }
        float w[8];
        #pragma unroll
        for (int i = 0; i < 8; i++) w[i] = src[(size_t)(kc * 8 + i) * N + n] * 16.f;
        unsigned int lo = 0, hi = 0;
        lo = enc2lo(w[0], w[1], lo); lo = enc2hi(w[2], w[3], lo);
        hi = enc2lo(w[4], w[5], hi); hi = enc2hi(w[6], w[7], hi);
        uint2 o; o.x = lo; o.y = hi;
        dst[(size_t)kc * N + n] = o;
    }
}

// ---------------------------------------------------------------------------
// Phase 1/3 GEMM: 128x128 tile, 4 waves (each 64x64 of 16x16x32 bf16 MFMA).
// A: (65536 x 512) bf16 row-major, m = b*512+t. Bt: (N x 512) bf16.
// MODE 0: store fp16 at out[(t*B+b)*N + n]  (time-major for recurrence)
// MODE 1: s[m] += sum_n relu(acc[m][n]) * wvec[n]  via atomicAdd into hvec[m]
// ---------------------------------------------------------------------------
template <int MODE>
__global__ __launch_bounds__(256)
void gemm128(const unsigned short* __restrict__ Abf, const unsigned short* __restrict__ Bt,
             int N, _Float16* __restrict__ outH,
             float* __restrict__ hvec, const float* __restrict__ wvec)
{
    __shared__ __align__(16) unsigned short As[128][40];
    __shared__ __align__(16) unsigned short Bs[128][40];
    const int tid = threadIdx.x;
    const int n0 = blockIdx.x * 128, m0 = blockIdx.y * 128;
    const int w = tid >> 6, lane = tid & 63;
    const int wm = (w & 1) * 64, wn = (w >> 1) * 64;
    const int fr = lane & 15, quad = lane >> 4;
    const int row = tid >> 1;                    // staging rows via 2 chunks
    f32x4 acc[4][4];
    #pragma unroll
    for (int i = 0; i < 4; i++)
        #pragma unroll
        for (int j = 0; j < 4; j++) acc[i][j] = (f32x4){0.f, 0.f, 0.f, 0.f};

    for (int k0 = 0; k0 < 512; k0 += 32) {
        uint4 av[2], bv[2];
        #pragma unroll
        for (int e = 0; e < 2; e++) {
            int chunk = e * 256 + tid;
            int r = chunk >> 2, kq = (chunk & 3) * 8;
            av[e] = *(const uint4*)(Abf + (size_t)(m0 + r) * 512 + k0 + kq);
            bv[e] = *(const uint4*)(Bt + (size_t)(n0 + r) * 512 + k0 + kq);
        }
        __syncthreads();
        #pragma unroll
        for (int e = 0; e < 2; e++) {
            int chunk = e * 256 + tid;
            int r = chunk >> 2, kq = (chunk & 3) * 8;
            *(uint4*)&As[r][kq] = av[e];
            *(uint4*)&Bs[r][kq] = bv[e];
        }
        __syncthreads();
        bf16x8 af[4], bf[4];
        #pragma unroll
        for (int mt = 0; mt < 4; mt++) af[mt] = *(const bf16x8*)&As[wm + mt * 16 + fr][quad * 8];
        #pragma unroll
        for (int nt = 0; nt < 4; nt++) bf[nt] = *(const bf16x8*)&Bs[wn + nt * 16 + fr][quad * 8];
        #pragma unroll
        for (int mt = 0; mt < 4; mt++)
            #pragma unroll
            for (int nt = 0; nt < 4; nt++)
                acc[mt][nt] = __builtin_amdgcn_mfma_f32_16x16x32_bf16(af[mt], bf[nt], acc[mt][nt], 0, 0, 0);
    }

    if (MODE == 0) {
        #pragma unroll
        for (int nt = 0; nt < 4; nt++) {
            int n = n0 + wn + nt * 16 + fr;
            #pragma unroll
            for (int mt = 0; mt < 4; mt++) {
                #pragma unroll
                for (int reg = 0; reg < 4; reg++) {
                    int m = m0 + wm + mt * 16 + quad * 4 + reg;
                    int b = m >> 9, t = m & 511;
                    outH[((size_t)t * Bn + b) * N + n] = (_Float16)acc[mt][nt][reg];
                }
            }
        }
    } else {
        float wv4[4];
        #pragma unroll
        for (int nt = 0; nt < 4; nt++) wv4[nt] = wvec[n0 + wn + nt * 16 + fr];
        #pragma unroll
        for (int mt = 0; mt < 4; mt++) {
            #pragma unroll
            for (int reg = 0; reg < 4; reg++) {
                float s = 0.f;
                #pragma unroll
                for (int nt = 0; nt < 4; nt++) s = fmaf(fmaxf(acc[mt][nt][reg], 0.f), wv4[nt], s);
                s += __shfl_xor(s, 1, 64);
                s += __shfl_xor(s, 2, 64);
                s += __shfl_xor(s, 4, 64);
                s += __shfl_xor(s, 8, 64);
                if (fr == 0) {
                    int m = m0 + wm + mt * 16 + quad * 4 + reg;
                    atomicAdd(&hvec[m], s);
                }
            }
        }
    }
}

__global__ __launch_bounds__(256)
void zero2(float* __restrict__ a, float* __restrict__ b)
{
    int i = blockIdx.x * 256 + threadIdx.x;
    a[i] = 0.f; b[i] = 0.f;
}

// ---------------------------------------------------------------------------
// Phase 2: recurrence. 128 WGs x 512 threads; WG = (dir, 2 batch rows).
// fp8 weights (x16 scale), packed-f32 FMA core; all state in LDS.
// h output stored bf16 into hsb[(b*512+t)*512 + d*256 + u].
// ---------------------------------------------------------------------------
__global__ __launch_bounds__(512)
void recurrence(const _Float16* __restrict__ xg,
                const _Float16* __restrict__ xWh,
                const _Float16* __restrict__ xWc,
                const uint2* __restrict__ rk8,
                const uint2* __restrict__ Wh8,
                const uint2* __restrict__ Wc8,
                unsigned short* __restrict__ hsb)
{
    const int tid = threadIdx.x;
    const int d = blockIdx.x >> 6;
    const int b0 = (blockIdx.x & 63) * 2;

    __shared__ float Hr[2][RS][Un], Cr[2][RS][Un];
    __shared__ float PHr[2][RS][Un], PCcr[2][RS][Un], PChr[2][RS][Un];
    __shared__ __align__(16) float hmS[2][Un];
    __shared__ float gtmp[2][4][Un];
    __shared__ float red[2][8][4];
    __shared__ float wsm[2][8];

    for (int e = tid; e < 2 * RS * Un; e += 512) {
        ((float*)Hr)[e] = 0.f; ((float*)Cr)[e] = 0.f;
        ((float*)PHr)[e] = 0.f; ((float*)PCcr)[e] = 0.f; ((float*)PChr)[e] = 0.f;
    }
    __syncthreads();

    const int r = tid >> 8, u = tid & 255;
    const int lane = tid & 63, wv = tid >> 6;
    const int q1 = tid >> 8, u1 = tid & 255;
    const uint2* p1g = rk8 + tid;
    const uint2* p2g = rk8 + tid + 512;

    for (int t = 0; t < Tn; t++) {
        const int tt = d ? (Tn - 1 - t) : t;
        const int st = t % RS;
        int sj[4];
        #pragma unroll
        for (int j = 0; j < 4; j++) sj[j] = (t - 1 - j + 2 * RS) % RS;

        const size_t rowx = (size_t)tt * Bn + (b0 + r);

        // early-issue: first 8 gate-weight chunks (loop-invariant addresses)
        uint2 gw1[8], gw2[8];
        #pragma unroll
        for (int j = 0; j < 8; j++) { gw1[j] = p1g[(size_t)j * 1024]; gw2[j] = p2g[(size_t)j * 1024]; }

        // step inputs
        float xh  = (float)xWh[rowx * Un + u];
        float xc  = (float)xWc[rowx * Un + u];
        float xg0 = (float)xg[rowx * Gn + u];
        float xg1 = (float)xg[rowx * Gn + Un + u];
        float xg2 = (float)xg[rowx * Gn + 2 * Un + u];
        float xg3 = (float)xg[rowx * Gn + 3 * Un + u];

        // ---- scores ----
        float vals[8];
        #pragma unroll
        for (int j = 0; j < 4; j++) {
            float ah = ftanh(PHr[r][sj[j]][u] + xh);
            vals[j] = ah * ah;
            float pc = (j < 3) ? PCcr[r][sj[j]][u] : PChr[r][sj[j]][u];
            float ac = ftanh(pc + ((j < 3) ? xc : xh));
            vals[4 + j] = ac * ac;
        }
        #pragma unroll
        for (int jj = 0; jj < 8; jj++) {
            float v = vals[jj];
            #pragma unroll
            for (int m = 32; m; m >>= 1) v += __shfl_xor(v, m, 64);
            if (lane == 0) red[r][jj][wv & 3] = v;
        }
        __syncthreads();
        if (tid < 4) {
            int rr = tid >> 1, hf = tid & 1;
            float s[4];
            #pragma unroll
            for (int j = 0; j < 4; j++) {
                const float* q = red[rr][hf * 4 + j];
                s[j] = sqrtf(q[0] + q[1] + q[2] + q[3]);
            }
            softmax4(s);
            #pragma unroll
            for (int j = 0; j < 4; j++) wsm[rr][hf * 4 + j] = s[j];
        }
        __syncthreads();

        // ---- hmix / cmix ----
        float ha = 0.f, ca = 0.f;
        #pragma unroll
        for (int j = 0; j < 4; j++) {
            ha = fmaf(wsm[r][j],     Hr[r][sj[j]][u], ha);
            ca = fmaf(wsm[r][4 + j], Cr[r][sj[j]][u], ca);
        }
        float cmv = fmaxf(ca, 0.f);
        hmS[r][u] = fmaxf(ha, 0.f);
        __syncthreads();

        // ---- gate GEMV: cols tid and tid+512; both batch rows per weight ----
        vf2 A00 = {0.f, 0.f}, A01 = {0.f, 0.f}, A10 = {0.f, 0.f}, A11v = {0.f, 0.f};
        auto gate_body = [&](uint2 w1, uint2 w2, int kc) {
            vf2 d0 = cvt2lo(w1.x), d1 = cvt2hi(w1.x), d2 = cvt2lo(w1.y), d3 = cvt2hi(w1.y);
            vf2 e0 = cvt2lo(w2.x), e1 = cvt2hi(w2.x), e2 = cvt2lo(w2.y), e3 = cvt2hi(w2.y);
            float4 h0a = *(const float4*)&hmS[0][kc * 8];
            float4 h0b = *(const float4*)&hmS[0][kc * 8 + 4];
            float4 h1a = *(const float4*)&hmS[1][kc * 8];
            float4 h1b = *(const float4*)&hmS[1][kc * 8 + 4];
            vf2 H00 = {h0a.x, h0a.y}, H01 = {h0a.z, h0a.w}, H02 = {h0b.x, h0b.y}, H03 = {h0b.z, h0b.w};
            vf2 H10 = {h1a.x, h1a.y}, H11 = {h1a.z, h1a.w}, H12 = {h1b.x, h1b.y}, H13 = {h1b.z, h1b.w};
            A00 = fma2(d0, H00, A00); A00 = fma2(d1, H01, A00); A00 = fma2(d2, H02, A00); A00 = fma2(d3, H03, A00);
            A01 = fma2(e0, H00, A01); A01 = fma2(e1, H01, A01); A01 = fma2(e2, H02, A01); A01 = fma2(e3, H03, A01);
            A10 = fma2(d0, H10, A10); A10 = fma2(d1, H11, A10); A10 = fma2(d2, H12, A10); A10 = fma2(d3, H13, A10);
            A11v = fma2(e0, H10, A11v); A11v = fma2(e1, H11, A11v); A11v = fma2(e2, H12, A11v); A11v = fma2(e3, H13, A11v);
        };
        #pragma unroll
        for (int kc = 0; kc < 8; kc++) gate_body(gw1[kc], gw2[kc], kc);
        #pragma unroll 8
        for (int kc = 8; kc < 32; kc++) {
            uint2 w1 = p1g[(size_t)kc * 1024], w2 = p2g[(size_t)kc * 1024];
            gate_body(w1, w2, kc);
        }
        gtmp[0][q1][u1]     = (A00.x + A00.y) * 0.0625f;
        gtmp[0][q1 + 2][u1] = (A01.x + A01.y) * 0.0625f;
        gtmp[1][q1][u1]     = (A10.x + A10.y) * 0.0625f;
        gtmp[1][q1 + 2][u1] = (A11v.x + A11v.y) * 0.0625f;
        __syncthreads();

        // ---- gates epilogue (r,u) ----
        {
            float g0 = gtmp[r][0][u] + xg0;
            float g1 = gtmp[r][1][u] + xg1;
            float g2 = gtmp[r][2][u] + xg2;
            float g3 = gtmp[r][3][u] + xg3;
            float gi = hsig(g0), gf = hsig(g1), gm = hsig(g2), go = hsig(g3);
            float c = gf * cmv + gi * gm;
            float h = go * ftanh(c);
            Hr[r][st][u] = h;
            Cr[r][st][u] = c;
            hsb[((size_t)(b0 + r) * 512 + tt) * 512 + d * 256 + u] = f2bf(h);
        }
        __syncthreads();

        // ---- projection caches for the new state ----
        if (tid < 256) {
            const int c = tid;
            const uint2* pw = Wh8 + c;
            vf2 P0 = {0.f, 0.f}, P1 = {0.f, 0.f}, Q0 = {0.f, 0.f}, Q1 = {0.f, 0.f};
            #pragma unroll 8
            for (int kc = 0; kc < 32; kc++) {
                uint2 wv8 = pw[(size_t)kc * 256];
                vf2 d0 = cvt2lo(wv8.x), d1 = cvt2hi(wv8.x), d2 = cvt2lo(wv8.y), d3 = cvt2hi(wv8.y);
                float4 h0a = *(const float4*)&Hr[0][st][kc * 8];
                float4 h0b = *(const float4*)&Hr[0][st][kc * 8 + 4];
                float4 h1a = *(const float4*)&Hr[1][st][kc * 8];
                float4 h1b = *(const float4*)&Hr[1][st][kc * 8 + 4];
                float4 c0a = *(const float4*)&Cr[0][st][kc * 8];
                float4 c0b = *(const float4*)&Cr[0][st][kc * 8 + 4];
                float4 c1a = *(const float4*)&Cr[1][st][kc * 8];
                float4 c1b = *(const float4*)&Cr[1][st][kc * 8 + 4];
                P0 = fma2(d0, (vf2){h0a.x, h0a.y}, P0); P0 = fma2(d1, (vf2){h0a.z, h0a.w}, P0);
                P0 = fma2(d2, (vf2){h0b.x, h0b.y}, P0); P0 = fma2(d3, (vf2){h0b.z, h0b.w}, P0);
                P1 = fma2(d0, (vf2){h1a.x, h1a.y}, P1); P1 = fma2(d1, (vf2){h1a.z, h1a.w}, P1);
                P1 = fma2(d2, (vf2){h1b.x, h1b.y}, P1); P1 = fma2(d3, (vf2){h1b.z, h1b.w}, P1);
                Q0 = fma2(d0, (vf2){c0a.x, c0a.y}, Q0); Q0 = fma2(d1, (vf2){c0a.z, c0a.w}, Q0);
                Q0 = fma2(d2, (vf2){c0b.x, c0b.y}, Q0); Q0 = fma2(d3, (vf2){c0b.z, c0b.w}, Q0);
                Q1 = fma2(d0, (vf2){c1a.x, c1a.y}, Q1); Q1 = fma2(d1, (vf2){c1a.z, c1a.w}, Q1);
                Q1 = fma2(d2, (vf2){c1b.x, c1b.y}, Q1); Q1 = fma2(d3, (vf2){c1b.z, c1b.w}, Q1);
            }
            PHr[0][st][c]  = (P0.x + P0.y) * 0.0625f;
            PHr[1][st][c]  = (P1.x + P1.y) * 0.0625f;
            PChr[0][st][c] = (Q0.x + Q0.y) * 0.0625f;
            PChr[1][st][c] = (Q1.x + Q1.y) * 0.0625f;
        } else {
            const int c = tid - 256;
            const uint2* pw = Wc8 + c;
            vf2 Q0 = {0.f, 0.f}, Q1 = {0.f, 0.f};
            #pragma unroll 8
            for (int kc = 0; kc < 32; kc++) {
                uint2 wv8 = pw[(size_t)kc * 256];
                vf2 d0 = cvt2lo(wv8.x), d1 = cvt2hi(wv8.x), d2 = cvt2lo(wv8.y), d3 = cvt2hi(wv8.y);
                float4 c0a = *(const float4*)&Cr[0][st][kc * 8];
                float4 c0b = *(const float4*)&Cr[0][st][kc * 8 + 4];
                float4 c1a = *(const float4*)&Cr[1][st][kc * 8];
                float4 c1b = *(const float4*)&Cr[1][st][kc * 8 + 4];
                Q0 = fma2(d0, (vf2){c0a.x, c0a.y}, Q0); Q0 = fma2(d1, (vf2){c0a.z, c0a.w}, Q0);
                Q0 = fma2(d2, (vf2){c0b.x, c0b.y}, Q0); Q0 = fma2(d3, (vf2){c0b.z, c0b.w}, Q0);
                Q1 = fma2(d0, (vf2){c1a.x, c1a.y}, Q1); Q1 = fma2(d1, (vf2){c1a.z, c1a.w}, Q1);
                Q1 = fma2(d2, (vf2){c1b.x, c1b.y}, Q1); Q1 = fma2(d3, (vf2){c1b.z, c1b.w}, Q1);
            }
            PCcr[0][st][c] = (Q0.x + Q0.y) * 0.0625f;
            PCcr[1][st][c] = (Q1.x + Q1.y) * 0.0625f;
        }
        __syncthreads();
    }
}

// ---------------------------------------------------------------------------
// Phase 4: out[m][k] = tanh(ha[m] * outs[m][k] + hb[m]); outs from hsb (bf16)
// ---------------------------------------------------------------------------
__global__ __launch_bounds__(256)
void final_ew(const unsigned short* __restrict__ hsb,
              const float* __restrict__ ha, const float* __restrict__ hb,
              float* __restrict__ out)
{
    size_t e = ((size_t)blockIdx.x * 256 + threadIdx.x) * 8;
    int m = (int)(e >> 9);
    float am = ha[m], bm = hb[m];
    uint4 hv = *(const uint4*)(hsb + e);
    unsigned int ws[4] = {hv.x, hv.y, hv.z, hv.w};
    float4 o0, o1;
    float* op0 = &o0.x;
    float* op1 = &o1.x;
    #pragma unroll
    for (int i = 0; i < 4; i++) {
        float vlo = __builtin_bit_cast(float, ws[i] << 16);
        float vhi = __builtin_bit_cast(float, ws[i] & 0xFFFF0000u);
        float rlo = ftanh(fmaf(am, vlo, bm));
        float rhi = ftanh(fmaf(am, vhi, bm));
        if (i < 2) { op0[i * 2] = rlo; op0[i * 2 + 1] = rhi; }
        else       { op1[(i - 2) * 2] = rlo; op1[(i - 2) * 2 + 1] = rhi; }
    }
    *(float4*)(out + e) = o0;
    *(float4*)(out + e + 4) = o1;
}

// ---------------------------------------------------------------------------
extern "C" void kernel_launch(void* const* d_in, const int* in_sizes, int n_in,
                              void* d_out, int out_size, void* d_ws, size_t ws_size,
                              hipStream_t stream)
{
    (void)in_sizes; (void)n_in; (void)out_size; (void)ws_size;
    const float* x    = (const float*)d_in[0];
    const float* wk   = (const float*)d_in[1];  // kernel (F, 4U)
    const float* rk   = (const float*)d_in[2];  // recurrent_kernel (U, 4U)
    const float* ath  = (const float*)d_in[3];  // attention_h (F+U, U)
    const float* atc  = (const float*)d_in[4];  // attention_c (F+U, U)
    const float* at1  = (const float*)d_in[5];  // attention1 (2U+F, U)
    const float* at2  = (const float*)d_in[7];  // attention2 (U, 1)
    const float* at22 = (const float*)d_in[8];  // attention2_2 (U, 1)
    float* out = (float*)d_out;

    char* p = (char*)d_ws;
    auto take = [&](size_t bytes) { char* q = p; p += (bytes + 255) & ~(size_t)255; return q; };
    _Float16* xg  = (_Float16*)take((size_t)Tn * Bn * Gn * 2);        // 134 MB
    _Float16* xWh = (_Float16*)take((size_t)Tn * Bn * Un * 2);        //  33 MB
    _Float16* xWc = (_Float16*)take((size_t)Tn * Bn * Un * 2);
    unsigned short* xbf = (unsigned short*)take((size_t)Bn * Tn * Fn * 2);   // 67 MB
    unsigned short* hsb = (unsigned short*)take((size_t)Bn * Tn * 512 * 2);  // 67 MB
    float* hav = (float*)take((size_t)Bn * Tn * 4);                   // 0.26 MB
    float* hbv = (float*)take((size_t)Bn * Tn * 4);
    uint2* rk8 = (uint2*)take((size_t)32 * 1024 * 8);                 // 256 KB
    uint2* Wh8 = (uint2*)take((size_t)32 * 256 * 8);
    uint2* Wc8 = (uint2*)take((size_t)32 * 256 * 8);
    unsigned short* Wt1  = (unsigned short*)take((size_t)Gn * Fn * 2);
    unsigned short* Wt2  = (unsigned short*)take((size_t)Un * Fn * 2);
    unsigned short* Wt3  = (unsigned short*)take((size_t)Un * Fn * 2);
    unsigned short* A11t = (unsigned short*)take((size_t)Un * Fn * 2);
    unsigned short* A12t = (unsigned short*)take((size_t)Un * Fn * 2);

    // Phase 0: packing
    pack_x<<<(Bn * Tn * Fn) / (256 * 4), 256, 0, stream>>>(x, xbf);
    wt_pack<<<2048, 256, 0, stream>>>(wk, Wt1, Gn);
    wt_pack<<<1024, 256, 0, stream>>>(ath + (size_t)Un * Un, Wt2, Un);
    wt_pack<<<1024, 256, 0, stream>>>(atc + (size_t)Un * Un, Wt3, Un);
    wt_pack<<<1024, 256, 0, stream>>>(at1, A11t, Un);
    wt_pack<<<1024, 256, 0, stream>>>(at1 + (size_t)512 * Un, A12t, Un);
    pack_w8<<<192, 256, 0, stream>>>(rk, ath, atc, rk8, Wh8, Wc8);
    zero2<<<(Bn * Tn) / 256, 256, 0, stream>>>(hav, hbv);

    // Phase 1: MFMA x-projections
    gemm128<0><<<dim3(Gn / 128, (Bn * Tn) / 128), 256, 0, stream>>>(xbf, Wt1, Gn, xg, nullptr, nullptr);
    gemm128<0><<<dim3(Un / 128, (Bn * Tn) / 128), 256, 0, stream>>>(xbf, Wt2, Un, xWh, nullptr, nullptr);
    gemm128<0><<<dim3(Un / 128, (Bn * Tn) / 128), 256, 0, stream>>>(xbf, Wt3, Un, xWc, nullptr, nullptr);

    // Phase 2: recurrence (fp8 weights)
    recurrence<<<dim3(128), dim3(512), 0, stream>>>(xg, xWh, xWc, rk8, Wh8, Wc8, hsb);

    // Phase 3: output attention via MFMA + fused relu.a2 row-reduce
    gemm128<1><<<dim3(Un / 128, (Bn * Tn) / 128), 256, 0, stream>>>(hsb, A11t, Un, nullptr, hav, at2);
    gemm128<1><<<dim3(Un / 128, (Bn * Tn) / 128), 256, 0, stream>>>(xbf, A12t, Un, nullptr, hbv, at22);

    // Phase 4: elementwise tanh
    final_ew<<<(Bn * Tn * 512) / (256 * 8), 256, 0, stream>>>(hsb, hav, hbv, out);
}